// Round 15
// baseline (325.564 us; speedup 1.0000x reference)
//
#include <hip/hip_runtime.h>

#define TPB 256
#define ROWN 8192
#define CAND_MAX 1024
#define EPS_TINY 1.1754943508222875e-38f   // np.finfo(np.float32).tiny

__device__ __forceinline__ unsigned rotl32(unsigned x, int r) {
  return (x << r) | (x >> (32 - r));
}

// threefry2x32, key (0,42), partitionable counters: ctr=(0,idx), bits = x0^x1.
// Verified on-device (r11 decode; r12-r14 absmax 0.0).
__device__ __forceinline__ unsigned tf_pxor(unsigned idx) {
  const unsigned ks0 = 0u, ks1 = 42u, ks2 = 0x1BD11BDAu ^ 0u ^ 42u;
  unsigned x0 = ks0;
  unsigned x1 = idx + ks1;
#define TF4(a,b,cc,d) \
  x0 += x1; x1 = rotl32(x1,(a));  x1 ^= x0; \
  x0 += x1; x1 = rotl32(x1,(b));  x1 ^= x0; \
  x0 += x1; x1 = rotl32(x1,(cc)); x1 ^= x0; \
  x0 += x1; x1 = rotl32(x1,(d));  x1 ^= x0;
  TF4(13,15,26,6)   x0 += ks1; x1 += ks2 + 1u;
  TF4(17,29,16,24)  x0 += ks2; x1 += ks0 + 2u;
  TF4(13,15,26,6)   x0 += ks0; x1 += ks1 + 3u;
  TF4(17,29,16,24)  x0 += ks1; x1 += ks2 + 4u;
  TF4(13,15,26,6)   x0 += ks2; x1 += ks0 + 5u;
#undef TF4
  return x0 ^ x1;
}

// EXACT jax gumbel (ocml precise logf) — used only for candidates (bit-exact).
__device__ __forceinline__ float gumbel_of(unsigned idx) {
  const unsigned bits = tf_pxor(idx);
  float u = __uint_as_float((bits >> 9) | 0x3f800000u) - 1.0f;
  u = u + EPS_TINY;
  u = fmaxf(EPS_TINY, u);
  return -logf(-logf(u));
}

// APPROX gumbel for the filter pass: |g_approx - g_exact| <= ~8e-4 guaranteed.
// u >= 0.75: t = -ln u via 5-term series in v = 1-u (exact by Sterbenz);
//            rel err <= v^5/6 = 1.6e-4. Robust near u -> 1.
// u <  0.75: t = -ln2*log2(u), |log2 u| >= 0.415 -> HW log error negligible.
// Then g = -ln t = -ln2*log2(t) with t in [1.2e-7, 87.3], never near the
// ill-conditioned t~1-with-tiny-result case in a way that exceeds 1e-4.
__device__ __forceinline__ float approx_gumbel(unsigned bits) {
  float u = __uint_as_float((bits >> 9) | 0x3f800000u) - 1.0f;
  u = u + EPS_TINY;
  u = fmaxf(EPS_TINY, u);
  float t;
  if (u >= 0.75f) {
    const float v = 1.0f - u;   // exact (Sterbenz)
    t = v * (1.0f + v * (0.5f + v * (0.33333334f + v * (0.25f + v * 0.2f))));
  } else {
    t = -0.69314718f * __log2f(u);   // v_log_f32
  }
  return -0.69314718f * __log2f(t);
}

// ---------------- k1: one block per row ----------------
__global__ __launch_bounds__(TPB)
void topk_rows(const void* __restrict__ scores_raw,
               unsigned* __restrict__ ws_idx,   // [2048][32] selected indices
               float* __restrict__ out_direct,  // fallback path
               int use_ws) {
  const int t    = threadIdx.x;
  const int lane = t & 63;
  const int wave = t >> 6;

  // XCD swizzle: the 8 rows sharing b (4e x 2rep) land on one XCD for L2 reuse.
  const int i   = blockIdx.x;           // 0..2047
  const int xcd = i & 7;
  const int k   = i >> 3;               // 0..255
  const int b   = xcd + 8 * (k >> 3);   // b % 8 == xcd
  const int mem = k & 7;
  const int e   = mem & 3;
  const int rep = mem >> 2;
  const int r   = rep * 1024 + b * 4 + e;

  __shared__ float    cf[CAND_MAX];
  __shared__ float    ckh[CAND_MAX];
  __shared__ int      cidx[CAND_MAX];
  __shared__ unsigned bm[ROWN / 32];    // 1 KB, fallback bitmap
  __shared__ int      sellist[32];
  __shared__ float    redM[4];
  __shared__ float    redZ[4];
  __shared__ float    redV[4];
  __shared__ int      redI[4];
  __shared__ int      redS[4];
  __shared__ int      wtot[4];
  __shared__ int      f32flag;

  // input dtype autodetect (4 KB prefix; proven r11-r14)
  if (t == 0) f32flag = 0;
  __syncthreads();
  {
    const unsigned* w = (const unsigned*)scores_raw;
    bool bad = false;
#pragma unroll
    for (int q = 0; q < 4; ++q) {
      const unsigned x = w[t + 256 * q];
      const float lo = __uint_as_float((x & 0xFFFFu) << 16);
      const float hi = __uint_as_float(x & 0xFFFF0000u);
      if (!(fabsf(lo) <= 16.0f) || !(fabsf(hi) <= 16.0f)) bad = true;
    }
    if (bad) f32flag = 1;
  }
  __syncthreads();
  const bool in_f32 = (f32flag != 0);

  // ---- gen (approx filter values; fully unrolled -> registers) ----
  const unsigned gbase = (unsigned)r * (unsigned)ROWN;
  const size_t ebase0 = ((size_t)b * ROWN + (size_t)t) * 4 + (size_t)e;
  float f[32];
  if (in_f32) {
    const float* sp = (const float*)scores_raw;
#pragma unroll
    for (int j = 0; j < 32; ++j)
      f[j] = sp[ebase0 + (size_t)(256 * j) * 4]
           + approx_gumbel(tf_pxor(gbase + (unsigned)(t + 256 * j)));
  } else {
    const unsigned short* sp = (const unsigned short*)scores_raw;
#pragma unroll
    for (int j = 0; j < 32; ++j)
      f[j] = __uint_as_float(((unsigned)sp[ebase0 + (size_t)(256 * j) * 4]) << 16)
           + approx_gumbel(tf_pxor(gbase + (unsigned)(t + 256 * j)));
  }

  // ---- block max of approx f ----
  float m = f[0];
#pragma unroll
  for (int j = 1; j < 32; ++j) m = fmaxf(m, f[j]);
#pragma unroll
  for (int off = 32; off >= 1; off >>= 1) m = fmaxf(m, __shfl_xor(m, off));
  if (lane == 0) redM[wave] = m;
  __syncthreads();
  m = fmaxf(fmaxf(redM[0], redM[1]), fmaxf(redM[2], redM[3]));
  __syncthreads();

  // ---- bisect theta33 on approx f ----
  float lo = m - 25.0f, hi = m;
#pragma unroll 1
  for (int itb = 0; itb < 14; ++itb) {
    const float mid = 0.5f * (lo + hi);
    int c = 0;
#pragma unroll
    for (int j = 0; j < 32; ++j) c += (f[j] > mid) ? 1 : 0;
#pragma unroll
    for (int off = 32; off >= 1; off >>= 1) c += __shfl_xor(c, off);
    if (lane == 0) wtot[wave] = c;
    __syncthreads();
    const int tot = wtot[0] + wtot[1] + wtot[2] + wtot[3];
    __syncthreads();
    if (tot >= 33) lo = mid; else hi = mid;
  }
  // theta covers all possibly-penalized / possible top-32 elements even with
  // approx error (2.3 dynamics margin + 0.02 >> 8e-4 approx bound).
  const float theta = lo - 2.32f;

  // ---- compact candidates; EXACT f recompute for candidates only ----
  int cj = 0;
#pragma unroll
  for (int j = 0; j < 32; ++j) cj += (f[j] > theta) ? 1 : 0;
  int inc = cj;
#pragma unroll
  for (int off = 1; off < 64; off <<= 1) {
    const int v = __shfl_up(inc, off);
    if (lane >= off) inc += v;
  }
  if (lane == 63) wtot[wave] = inc;
  __syncthreads();
  int base = 0;
  for (int w = 0; w < wave; ++w) base += wtot[w];
  int cnt = wtot[0] + wtot[1] + wtot[2] + wtot[3];
  if (cnt > CAND_MAX) cnt = CAND_MAX;
  int o = base + inc - cj;
  __syncthreads();
#pragma unroll
  for (int j = 0; j < 32; ++j) {
    if (f[j] > theta) {
      if (o < CAND_MAX) {
        const int n = t + 256 * j;
        float sc;
        if (in_f32) sc = ((const float*)scores_raw)[ebase0 + (size_t)(256 * j) * 4];
        else sc = __uint_as_float(((unsigned)((const unsigned short*)scores_raw)[ebase0 + (size_t)(256 * j) * 4]) << 16);
        cidx[o] = n;
        cf[o]   = sc + gumbel_of(gbase + (unsigned)n);   // bit-exact
        ckh[o]  = 0.0f;
      }
      ++o;
    }
  }
  __syncthreads();

  // ---- 32 np-faithful dynamics iterations on candidates (3 barriers/iter) ----
#pragma unroll 1
  for (int it = 0; it < 32; ++it) {
    float lm = -3.4e38f;
#pragma unroll
    for (int kk = 0; kk < 4; ++kk) {
      const int ci = t + 256 * kk;
      if (ci < cnt) lm = fmaxf(lm, cf[ci]);
    }
#pragma unroll
    for (int off = 32; off >= 1; off >>= 1) lm = fmaxf(lm, __shfl_xor(lm, off));
    if (lane == 0) redM[wave] = lm;
    __syncthreads();                                   // B1
    const float m2 = fmaxf(fmaxf(redM[0], redM[1]), fmaxf(redM[2], redM[3]));
    const float xm = m2 / 0.1f;

    float ek[4];
    float ls = 0.0f;
#pragma unroll
    for (int kk = 0; kk < 4; ++kk) {
      const int ci = t + 256 * kk;
      float ev = 0.0f;
      if (ci < cnt) {
        const float fv = cf[ci];
        if (fv - m2 > -10.398f) { ev = expf(fv / 0.1f - xm); ls += ev; }
      }
      ek[kk] = ev;
    }
#pragma unroll
    for (int off = 32; off >= 1; off >>= 1) ls += __shfl_xor(ls, off);
    if (lane == 0) redZ[wave] = ls;
    __syncthreads();                                   // B2
    const float Z = (redZ[0] + redZ[1]) + (redZ[2] + redZ[3]);

#pragma unroll
    for (int kk = 0; kk < 4; ++kk) {
      const int ci = t + 256 * kk;
      if (ci < cnt && ek[kk] > 0.0f) {
        const float p = ek[kk] / Z;
        ckh[ci] += p;
        const float msk = 1.0f - p;
        if (msk != 1.0f) cf[ci] += logf(fmaxf(msk, EPS_TINY));
      }
    }
    __syncthreads();                                   // B3
  }

  // ---- top-32 of khot (lowest-n tie-break) ----
#pragma unroll 1
  for (int pass = 0; pass < 32; ++pass) {
    float bv = -3.4e38f; int bi = 0x7FFFFFFF, bs = 0;
#pragma unroll
    for (int kk = 0; kk < 4; ++kk) {
      const int ci = t + 256 * kk;
      if (ci < cnt) {
        const float v = ckh[ci];
        const int ix = cidx[ci];
        if (v > bv || (v == bv && ix < bi)) { bv = v; bi = ix; bs = ci; }
      }
    }
#pragma unroll
    for (int off = 32; off >= 1; off >>= 1) {
      const float ov = __shfl_xor(bv, off);
      const int   oi = __shfl_xor(bi, off);
      const int   os = __shfl_xor(bs, off);
      if (ov > bv || (ov == bv && oi < bi)) { bv = ov; bi = oi; bs = os; }
    }
    if (lane == 0) { redV[wave] = bv; redI[wave] = bi; redS[wave] = bs; }
    __syncthreads();
    if (t == 0) {
      float wv = redV[0]; int wi = redI[0], ws = redS[0];
#pragma unroll
      for (int w = 1; w < 4; ++w) {
        const float ov = redV[w]; const int oi = redI[w], os = redS[w];
        if (ov > wv || (ov == wv && oi < wi)) { wv = ov; wi = oi; ws = os; }
      }
      sellist[pass] = wi;
      ckh[ws] = -3.4e38f;
    }
    __syncthreads();
  }

  if (use_ws) {
    if (t < 32) ws_idx[r * 32 + t] = (unsigned)sellist[t];
  } else {
    if (t < ROWN / 32) bm[t] = 0u;
    __syncthreads();
    if (t == 0) {
#pragma unroll 1
      for (int p = 0; p < 32; ++p) {
        const int ix = sellist[p];
        bm[ix >> 5] |= (1u << (ix & 31));
      }
    }
    __syncthreads();
    float* op = out_direct + ((size_t)(rep * 256 + b) * ROWN) * 4 + (size_t)e;
#pragma unroll 1
    for (int j = 0; j < 32; ++j) {
      const int n = t + 256 * j;
      op[(size_t)n * 4] = ((bm[n >> 5] >> (n & 31)) & 1u) ? 1.0f : 0.0f;
    }
  }
}

// ---------------- k2: indices -> coalesced float4 output ----------------
__global__ __launch_bounds__(TPB)
void write_out(const unsigned* __restrict__ ws_idx, float4* __restrict__ out4) {
  const int t = threadIdx.x;
  const int i = blockIdx.x;        // 4096
  const int g = i >> 3;            // 0..511 = rep*256 + b
  const int slice = i & 7;         // 1024-wide n slice
  const int rep = g >> 8;
  const int b = g & 255;

  __shared__ unsigned bm[4][ROWN / 32];   // 4 KB
  __shared__ unsigned idxbuf[128];

#pragma unroll
  for (int q = 0; q < 4; ++q) ((unsigned*)bm)[t + 256 * q] = 0u;
  if (t < 128) {
    const int e = t >> 5, p = t & 31;
    idxbuf[t] = ws_idx[(size_t)(rep * 1024 + b * 4 + e) * 32 + p];
  }
  __syncthreads();
  if (t < 4) {
#pragma unroll 1
    for (int p = 0; p < 32; ++p) {
      const unsigned ix = idxbuf[t * 32 + p];
      bm[t][ix >> 5] |= (1u << (ix & 31));
    }
  }
  __syncthreads();

  const size_t obase = (size_t)g * ROWN;
#pragma unroll
  for (int j = 0; j < 4; ++j) {
    const int n = slice * 1024 + t + 256 * j;
    float4 v;
    v.x = ((bm[0][n >> 5] >> (n & 31)) & 1u) ? 1.0f : 0.0f;
    v.y = ((bm[1][n >> 5] >> (n & 31)) & 1u) ? 1.0f : 0.0f;
    v.z = ((bm[2][n >> 5] >> (n & 31)) & 1u) ? 1.0f : 0.0f;
    v.w = ((bm[3][n >> 5] >> (n & 31)) & 1u) ? 1.0f : 0.0f;
    out4[obase + (size_t)n] = v;
  }
}

extern "C" void kernel_launch(void* const* d_in, const int* in_sizes, int n_in,
                              void* d_out, int out_size, void* d_ws, size_t ws_size,
                              hipStream_t stream) {
  const void* scores = d_in[0];    // dtype autodetected in-kernel
  float* out = (float*)d_out;      // f32 output (established r11)
  const int use_ws = (ws_size >= 2048u * 32u * sizeof(unsigned)) ? 1 : 0;
  unsigned* wsi = (unsigned*)d_ws;
  topk_rows<<<dim3(2048), dim3(TPB), 0, stream>>>(scores, wsi, out, use_ws);
  if (use_ws)
    write_out<<<dim3(4096), dim3(TPB), 0, stream>>>(wsi, (float4*)out);
}

// Round 16
// 297.913 us; speedup vs baseline: 1.0928x; 1.0928x over previous
//
#include <hip/hip_runtime.h>

#define TPB 256
#define ROWN 8192
#define CAND_MAX 1024
#define EPS_TINY 1.1754943508222875e-38f   // np.finfo(np.float32).tiny

__device__ __forceinline__ unsigned rotl32(unsigned x, int r) {
  return (x << r) | (x >> (32 - r));
}

// threefry2x32, key (0,42), partitionable counters: ctr=(0,idx), bits = x0^x1.
// Verified on-device (r11 decode; r12-r15 absmax 0.0).
__device__ __forceinline__ unsigned tf_pxor(unsigned idx) {
  const unsigned ks0 = 0u, ks1 = 42u, ks2 = 0x1BD11BDAu ^ 0u ^ 42u;
  unsigned x0 = ks0;
  unsigned x1 = idx + ks1;
#define TF4(a,b,cc,d) \
  x0 += x1; x1 = rotl32(x1,(a));  x1 ^= x0; \
  x0 += x1; x1 = rotl32(x1,(b));  x1 ^= x0; \
  x0 += x1; x1 = rotl32(x1,(cc)); x1 ^= x0; \
  x0 += x1; x1 = rotl32(x1,(d));  x1 ^= x0;
  TF4(13,15,26,6)   x0 += ks1; x1 += ks2 + 1u;
  TF4(17,29,16,24)  x0 += ks2; x1 += ks0 + 2u;
  TF4(13,15,26,6)   x0 += ks0; x1 += ks1 + 3u;
  TF4(17,29,16,24)  x0 += ks1; x1 += ks2 + 4u;
  TF4(13,15,26,6)   x0 += ks2; x1 += ks0 + 5u;
#undef TF4
  return x0 ^ x1;
}

// EXACT jax gumbel (precise ocml logf) — executed wave-dense for candidates only.
__device__ __forceinline__ float gumbel_of(unsigned idx) {
  const unsigned bits = tf_pxor(idx);
  float u = __uint_as_float((bits >> 9) | 0x3f800000u) - 1.0f;
  u = u + EPS_TINY;
  u = fmaxf(EPS_TINY, u);
  return -logf(-logf(u));
}

// APPROX gumbel for the filter pass: |err| <= ~2e-4 (series rel err v^5/6
// for u>=0.75 with Sterbenz-exact v=1-u; HW v_log_f32 elsewhere).
__device__ __forceinline__ float approx_gumbel(unsigned bits) {
  float u = __uint_as_float((bits >> 9) | 0x3f800000u) - 1.0f;
  u = u + EPS_TINY;
  u = fmaxf(EPS_TINY, u);
  float t;
  if (u >= 0.75f) {
    const float v = 1.0f - u;   // exact (Sterbenz)
    t = v * (1.0f + v * (0.5f + v * (0.33333334f + v * (0.25f + v * 0.2f))));
  } else {
    t = -0.69314718f * __log2f(u);   // v_log_f32
  }
  return -0.69314718f * __log2f(t);
}

// ---------------- k1: one block per row ----------------
__global__ __launch_bounds__(TPB)
void topk_rows(const void* __restrict__ scores_raw,
               unsigned* __restrict__ ws_idx,   // [2048][32] selected indices
               float* __restrict__ out_direct,  // fallback path
               int use_ws) {
  const int t    = threadIdx.x;
  const int lane = t & 63;
  const int wave = t >> 6;

  // XCD swizzle: the 8 rows sharing b (4e x 2rep) land on one XCD for L2 reuse.
  const int i   = blockIdx.x;           // 0..2047
  const int xcd = i & 7;
  const int k   = i >> 3;               // 0..255
  const int b   = xcd + 8 * (k >> 3);   // b % 8 == xcd
  const int mem = k & 7;
  const int e   = mem & 3;
  const int rep = mem >> 2;
  const int r   = rep * 1024 + b * 4 + e;

  __shared__ float    cf[CAND_MAX];
  __shared__ float    ckh[CAND_MAX];
  __shared__ int      cidx[CAND_MAX];
  __shared__ unsigned bm[ROWN / 32];    // 1 KB, fallback bitmap
  __shared__ int      sellist[32];
  __shared__ float    redM[4];
  __shared__ float    redZ[4];
  __shared__ float    redV[4];
  __shared__ int      redI[4];
  __shared__ int      redS[4];
  __shared__ int      wtot[4];
  __shared__ int      f32flag;

  // input dtype autodetect (4 KB prefix; proven r11-r15)
  if (t == 0) f32flag = 0;
  __syncthreads();
  {
    const unsigned* w = (const unsigned*)scores_raw;
    bool bad = false;
#pragma unroll
    for (int q = 0; q < 4; ++q) {
      const unsigned x = w[t + 256 * q];
      const float lo = __uint_as_float((x & 0xFFFFu) << 16);
      const float hi = __uint_as_float(x & 0xFFFF0000u);
      if (!(fabsf(lo) <= 16.0f) || !(fabsf(hi) <= 16.0f)) bad = true;
    }
    if (bad) f32flag = 1;
  }
  __syncthreads();
  const bool in_f32 = (f32flag != 0);

  // ---- gen (approx filter values; fully unrolled -> registers) ----
  const unsigned gbase = (unsigned)r * (unsigned)ROWN;
  const size_t ebase0 = ((size_t)b * ROWN + (size_t)t) * 4 + (size_t)e;
  float f[32];
  if (in_f32) {
    const float* sp = (const float*)scores_raw;
#pragma unroll
    for (int j = 0; j < 32; ++j)
      f[j] = sp[ebase0 + (size_t)(256 * j) * 4]
           + approx_gumbel(tf_pxor(gbase + (unsigned)(t + 256 * j)));
  } else {
    const unsigned short* sp = (const unsigned short*)scores_raw;
#pragma unroll
    for (int j = 0; j < 32; ++j)
      f[j] = __uint_as_float(((unsigned)sp[ebase0 + (size_t)(256 * j) * 4]) << 16)
           + approx_gumbel(tf_pxor(gbase + (unsigned)(t + 256 * j)));
  }

  // ---- block max of approx f ----
  float m = f[0];
#pragma unroll
  for (int j = 1; j < 32; ++j) m = fmaxf(m, f[j]);
#pragma unroll
  for (int off = 32; off >= 1; off >>= 1) m = fmaxf(m, __shfl_xor(m, off));
  if (lane == 0) redM[wave] = m;
  __syncthreads();
  m = fmaxf(fmaxf(redM[0], redM[1]), fmaxf(redM[2], redM[3]));
  __syncthreads();

  // ---- bisect theta33 on approx f (12 iters, resolution 25/4096 = 6e-3) ----
  float lo = m - 25.0f, hi = m;
#pragma unroll 1
  for (int itb = 0; itb < 12; ++itb) {
    const float mid = 0.5f * (lo + hi);
    int c = 0;
#pragma unroll
    for (int j = 0; j < 32; ++j) c += (f[j] > mid) ? 1 : 0;
#pragma unroll
    for (int off = 32; off >= 1; off >>= 1) c += __shfl_xor(c, off);
    if (lane == 0) wtot[wave] = c;
    __syncthreads();
    const int tot = wtot[0] + wtot[1] + wtot[2] + wtot[3];
    __syncthreads();
    if (tot >= 33) lo = mid; else hi = mid;
  }
  // margin: 1.74 dynamics requirement + drift + bisect resolution + approx err
  const float theta = lo - 2.33f;

  // ---- compact candidate INDICES only (cheap divergent body) ----
  int cj = 0;
#pragma unroll
  for (int j = 0; j < 32; ++j) cj += (f[j] > theta) ? 1 : 0;
  int inc = cj;
#pragma unroll
  for (int off = 1; off < 64; off <<= 1) {
    const int v = __shfl_up(inc, off);
    if (lane >= off) inc += v;
  }
  if (lane == 63) wtot[wave] = inc;
  __syncthreads();
  int base = 0;
  for (int w = 0; w < wave; ++w) base += wtot[w];
  int cnt = wtot[0] + wtot[1] + wtot[2] + wtot[3];
  if (cnt > CAND_MAX) cnt = CAND_MAX;
  int o = base + inc - cj;
  __syncthreads();
#pragma unroll
  for (int j = 0; j < 32; ++j) {
    if (f[j] > theta) {
      if (o < CAND_MAX) cidx[o] = t + 256 * j;
      ++o;
    }
  }
  __syncthreads();

  // ---- dense EXACT recompute for candidates (wave-dense: ~6 waves active) ----
#pragma unroll
  for (int kk = 0; kk < 4; ++kk) {
    const int ci = t + 256 * kk;
    if (ci < cnt) {
      const int n = cidx[ci];
      const size_t ei = ((size_t)b * ROWN + (size_t)n) * 4 + (size_t)e;
      float sc;
      if (in_f32) sc = ((const float*)scores_raw)[ei];
      else sc = __uint_as_float(((unsigned)((const unsigned short*)scores_raw)[ei]) << 16);
      cf[ci]  = sc + gumbel_of(gbase + (unsigned)n);   // bit-exact
      ckh[ci] = 0.0f;
    }
  }
  __syncthreads();

  // ---- 32 np-faithful dynamics iterations (3 barriers/iter) ----
#pragma unroll 1
  for (int it = 0; it < 32; ++it) {
    float lm = -3.4e38f;
#pragma unroll
    for (int kk = 0; kk < 4; ++kk) {
      const int ci = t + 256 * kk;
      if (ci < cnt) lm = fmaxf(lm, cf[ci]);
    }
#pragma unroll
    for (int off = 32; off >= 1; off >>= 1) lm = fmaxf(lm, __shfl_xor(lm, off));
    if (lane == 0) redM[wave] = lm;
    __syncthreads();                                   // B1
    const float m2 = fmaxf(fmaxf(redM[0], redM[1]), fmaxf(redM[2], redM[3]));
    const float xm = m2 / 0.1f;

    float ek[4];
    float ls = 0.0f;
#pragma unroll
    for (int kk = 0; kk < 4; ++kk) {
      const int ci = t + 256 * kk;
      float ev = 0.0f;
      if (ci < cnt) {
        const float fv = cf[ci];
        if (fv - m2 > -10.398f) { ev = expf(fv / 0.1f - xm); ls += ev; }
      }
      ek[kk] = ev;
    }
#pragma unroll
    for (int off = 32; off >= 1; off >>= 1) ls += __shfl_xor(ls, off);
    if (lane == 0) redZ[wave] = ls;
    __syncthreads();                                   // B2
    const float Z = (redZ[0] + redZ[1]) + (redZ[2] + redZ[3]);

#pragma unroll
    for (int kk = 0; kk < 4; ++kk) {
      const int ci = t + 256 * kk;
      if (ci < cnt && ek[kk] > 0.0f) {
        const float p = ek[kk] / Z;
        ckh[ci] += p;
        const float msk = 1.0f - p;
        if (msk != 1.0f) cf[ci] += logf(fmaxf(msk, EPS_TINY));
      }
    }
    __syncthreads();                                   // B3
  }

  // ---- top-32 of khot (lowest-n tie-break; handles khot==0 ties) ----
#pragma unroll 1
  for (int pass = 0; pass < 32; ++pass) {
    float bv = -3.4e38f; int bi = 0x7FFFFFFF, bs = 0;
#pragma unroll
    for (int kk = 0; kk < 4; ++kk) {
      const int ci = t + 256 * kk;
      if (ci < cnt) {
        const float v = ckh[ci];
        const int ix = cidx[ci];
        if (v > bv || (v == bv && ix < bi)) { bv = v; bi = ix; bs = ci; }
      }
    }
#pragma unroll
    for (int off = 32; off >= 1; off >>= 1) {
      const float ov = __shfl_xor(bv, off);
      const int   oi = __shfl_xor(bi, off);
      const int   os = __shfl_xor(bs, off);
      if (ov > bv || (ov == bv && oi < bi)) { bv = ov; bi = oi; bs = os; }
    }
    if (lane == 0) { redV[wave] = bv; redI[wave] = bi; redS[wave] = bs; }
    __syncthreads();
    if (t == 0) {
      float wv = redV[0]; int wi = redI[0], ws = redS[0];
#pragma unroll
      for (int w = 1; w < 4; ++w) {
        const float ov = redV[w]; const int oi = redI[w], os = redS[w];
        if (ov > wv || (ov == wv && oi < wi)) { wv = ov; wi = oi; ws = os; }
      }
      sellist[pass] = wi;
      ckh[ws] = -3.4e38f;
    }
    __syncthreads();
  }

  if (use_ws) {
    if (t < 32) ws_idx[r * 32 + t] = (unsigned)sellist[t];
  } else {
    if (t < ROWN / 32) bm[t] = 0u;
    __syncthreads();
    if (t == 0) {
#pragma unroll 1
      for (int p = 0; p < 32; ++p) {
        const int ix = sellist[p];
        bm[ix >> 5] |= (1u << (ix & 31));
      }
    }
    __syncthreads();
    float* op = out_direct + ((size_t)(rep * 256 + b) * ROWN) * 4 + (size_t)e;
#pragma unroll 1
    for (int j = 0; j < 32; ++j) {
      const int n = t + 256 * j;
      op[(size_t)n * 4] = ((bm[n >> 5] >> (n & 31)) & 1u) ? 1.0f : 0.0f;
    }
  }
}

// ---------------- k2: indices -> coalesced float4 output ----------------
__global__ __launch_bounds__(TPB)
void write_out(const unsigned* __restrict__ ws_idx, float4* __restrict__ out4) {
  const int t = threadIdx.x;
  const int i = blockIdx.x;        // 4096
  const int g = i >> 3;            // 0..511 = rep*256 + b
  const int slice = i & 7;         // 1024-wide n slice
  const int rep = g >> 8;
  const int b = g & 255;

  __shared__ unsigned bm[4][ROWN / 32];   // 4 KB
  __shared__ unsigned idxbuf[128];

#pragma unroll
  for (int q = 0; q < 4; ++q) ((unsigned*)bm)[t + 256 * q] = 0u;
  if (t < 128) {
    const int e = t >> 5, p = t & 31;
    idxbuf[t] = ws_idx[(size_t)(rep * 1024 + b * 4 + e) * 32 + p];
  }
  __syncthreads();
  if (t < 4) {
#pragma unroll 1
    for (int p = 0; p < 32; ++p) {
      const unsigned ix = idxbuf[t * 32 + p];
      bm[t][ix >> 5] |= (1u << (ix & 31));
    }
  }
  __syncthreads();

  const size_t obase = (size_t)g * ROWN;
#pragma unroll
  for (int j = 0; j < 4; ++j) {
    const int n = slice * 1024 + t + 256 * j;
    float4 v;
    v.x = ((bm[0][n >> 5] >> (n & 31)) & 1u) ? 1.0f : 0.0f;
    v.y = ((bm[1][n >> 5] >> (n & 31)) & 1u) ? 1.0f : 0.0f;
    v.z = ((bm[2][n >> 5] >> (n & 31)) & 1u) ? 1.0f : 0.0f;
    v.w = ((bm[3][n >> 5] >> (n & 31)) & 1u) ? 1.0f : 0.0f;
    out4[obase + (size_t)n] = v;
  }
}

extern "C" void kernel_launch(void* const* d_in, const int* in_sizes, int n_in,
                              void* d_out, int out_size, void* d_ws, size_t ws_size,
                              hipStream_t stream) {
  const void* scores = d_in[0];    // dtype autodetected in-kernel
  float* out = (float*)d_out;      // f32 output (established r11)
  const int use_ws = (ws_size >= 2048u * 32u * sizeof(unsigned)) ? 1 : 0;
  unsigned* wsi = (unsigned*)d_ws;
  topk_rows<<<dim3(2048), dim3(TPB), 0, stream>>>(scores, wsi, out, use_ws);
  if (use_ws)
    write_out<<<dim3(4096), dim3(TPB), 0, stream>>>(wsi, (float4*)out);
}